// Round 3
// baseline (172.207 us; speedup 1.0000x reference)
//
#include <hip/hip_runtime.h>
#include <hip/hip_fp16.h>
#include <math.h>

using f16    = _Float16;
using f16x8  = __attribute__((ext_vector_type(8))) _Float16;
using f32x16 = __attribute__((ext_vector_type(16))) float;

// ---------------- workspace layout (bytes) ----------------
// ewT : [8][9][q=8][co=128] 16B chunks (A pre-fragmented) = 1179648
// fw16: [128 co2][128 co] f16                             = 32768
#define EWT_OFF 0
#define FW_OFF  1179648

// ============ K0: weight transpose/convert ============
__global__ __launch_bounds__(256) void pce_prep(
    const float* __restrict__ ew, const float* __restrict__ fw, char* __restrict__ ws)
{
  int i = blockIdx.x * 256 + threadIdx.x;
  if (i < 73728) {                     // ewT: i = t*1024 + q*128 + co
    int co = i & 127, q = (i >> 7) & 7, t = i >> 10;
    int e = t / 9, tap = t - e * 9;
    const float* s = ew + ((size_t)((e * 128 + co) * 64 + q * 8)) * 9 + tap;
    f16x8 v;
#pragma unroll
    for (int j = 0; j < 8; ++j) v[j] = (f16)s[j * 9];
    *(f16x8*)(ws + EWT_OFF + (size_t)i * 16) = v;
  } else if (i < 73728 + 2048) {       // fw16
    int j = i - 73728;
    int pos = j & 15, co2 = j >> 4;
    const float* s = fw + co2 * 128 + pos * 8;
    f16x8 v;
#pragma unroll
    for (int k = 0; k < 8; ++k) v[k] = (f16)s[k];
    *(f16x8*)(ws + FW_OFF + (size_t)j * 16) = v;
  }
}

// ============ fused main kernel ============
// block = (b, patch, half). 256 thr = 4 waves. Output: 128co x 128px (8 rows x 16 cols).
// Phase 1: gated expert 3x3 convs (A from global L2, B from LDS, barrier-free K loop)
// Phase 2: 1x1 conv from LDS comb + bias + interior write. Border folded in.
// LDS: xs [10r][18c][64ci swz] = 23040 | comb [128px][128co swz] = 32768 | gates 32
#define XS_BYTES 23040
#define GSM_OFF  55808
__global__ __launch_bounds__(256, 2) void pce_main(
    const float* __restrict__ x, const float* __restrict__ eb,
    const float* __restrict__ rw, const float* __restrict__ rb,
    const float* __restrict__ thrp, const char* __restrict__ ws,
    const float* __restrict__ fb, float* __restrict__ out)
{
  __shared__ char sm[55840];
  const int tid = threadIdx.x;
  const int blk = blockIdx.x;
  const int b = blk / 72;
  const int r72 = blk - b * 72;
  const int patch = r72 >> 1, half = r72 & 1;
  const int py = patch / 6, px = patch - py * 6;

  // ---- border ring (1x1 conv w/ padding=1 -> pure bias), spread over blocks ----
  {
    const int total = 8 * 128 * 388;
    int base = blk * 690;
#pragma unroll 1
    for (int t = tid; t < 690; t += 256) {
      int idx = base + t;
      if (idx < total) {
        int seg = idx % 388;
        int bc  = idx / 388;
        int co  = bc & 127, bb = bc >> 7;
        int hh, wc;
        if      (seg < 98)  { hh = 0;             wc = seg; }
        else if (seg < 196) { hh = 97;            wc = seg - 98; }
        else if (seg < 292) { hh = seg - 196 + 1; wc = 0; }
        else                { hh = seg - 292 + 1; wc = 97; }
        out[((size_t)(bb * 128 + co) * 98 + hh) * 98 + wc] = fb[co];
      }
    }
  }

  // ---- stage x halo (10 rows x 18 cols) -> xs f16, chunk pos = (ci>>3)^(c&7) ----
  const int gy0 = py * 16 + half * 8 - 1, gx0 = px * 16 - 1;
#pragma unroll 1
  for (int ch = tid; ch < 1440; ch += 256) {
    int pos = ch & 7, p = ch >> 3;
    int rr = p / 18, c = p - rr * 18;
    int c8 = pos ^ (c & 7);
    int gy = gy0 + rr, gx = gx0 + c;
    f16x8 v;
#pragma unroll
    for (int j = 0; j < 8; ++j) v[j] = (f16)0.f;
    if ((unsigned)gy < 96u && (unsigned)gx < 96u) {
      const float* xp = x + ((size_t)(b * 64 + c8 * 8) * 96 + gy) * 96 + gx;
#pragma unroll
      for (int j = 0; j < 8; ++j) v[j] = (f16)xp[(size_t)j * 9216];
    }
    *(f16x8*)(sm + p * 128 + pos * 16) = v;
  }

  // ---- gates (every thread computes all 8; thread e stores gate e) ----
  int mask;
  {
    float sy[8], cy[8], sx[8], cx[8];
    float pyc = ((float)py + 0.5f) * (1.f / 6.f);
    float pxc = ((float)px + 0.5f) * (1.f / 6.f);
#pragma unroll
    for (int k = 0; k < 8; ++k) {
      float fr = (float)(1 << k) * 3.14159265358979323846f;
      sy[k] = sinf(pyc * fr); cy[k] = cosf(pyc * fr);
      sx[k] = sinf(pxc * fr); cx[k] = cosf(pxc * fr);
    }
    float thr = thrp[0];
    unsigned m = 0;
#pragma unroll
    for (int e = 0; e < 8; ++e) {
      float l = rb[e];
#pragma unroll
      for (int k = 0; k < 8; ++k) {
        l = fmaf(sy[k], rw[e * 32 + k],      l);
        l = fmaf(cy[k], rw[e * 32 + 8 + k],  l);
        l = fmaf(sx[k], rw[e * 32 + 16 + k], l);
        l = fmaf(cx[k], rw[e * 32 + 24 + k], l);
      }
      float g = 1.f / (1.f + expf(-l));
      g = (g > thr) ? g : 0.f;
      if (tid == e) ((float*)(sm + GSM_OFF))[e] = g;
      m |= (g != 0.f ? 1u : 0u) << e;
    }
    mask = __builtin_amdgcn_readfirstlane((int)m);
  }

  const int lane = tid & 63, wv = tid >> 6;
  const int l31 = lane & 31, l5 = lane >> 5;
  const int m0 = (wv & 1) * 64;          // co tile   (wave pairs share -> L1 reuse)
  const int n0 = (wv >> 1) * 64;         // pixel tile
  const int tx = l31 & 15;
  const int tyb0 = (n0 >> 4) + (l31 >> 4);
  const int tyb1 = tyb0 + 2;

  const char* ewt = ws + EWT_OFF;
  f16x8 A0[2][4], A1[2][4];
  f32x16 acc[2][2];
  __half2 comb[2][2][8];
#pragma unroll
  for (int mi = 0; mi < 2; ++mi)
#pragma unroll
    for (int ni = 0; ni < 2; ++ni)
#pragma unroll
      for (int h = 0; h < 8; ++h) comb[mi][ni][h] = __floats2half2_rn(0.f, 0.f);

  auto LDA = [&](f16x8 (&A)[2][4], int t) {
    const char* s = ewt + (size_t)t * 16384;
#pragma unroll
    for (int mi = 0; mi < 2; ++mi)
#pragma unroll
      for (int ks = 0; ks < 4; ++ks)
        A[mi][ks] = *(const f16x8*)(s + ((ks * 2 + l5) * 128 + m0 + mi * 32 + l31) * 16);
  };
  auto TAP = [&](int ky, int kx, const f16x8 (&A)[2][4]) {
    const int cc = tx + kx, sw = cc & 7;
    const int r0 = ((tyb0 + ky) * 18 + cc) * 128;
    const int r1 = ((tyb1 + ky) * 18 + cc) * 128;
#pragma unroll
    for (int ks = 0; ks < 4; ++ks) {
      const int co = (((ks << 1) | l5) ^ sw) << 4;
      f16x8 bv0 = *(const f16x8*)(sm + r0 + co);
      f16x8 bv1 = *(const f16x8*)(sm + r1 + co);
      acc[0][0] = __builtin_amdgcn_mfma_f32_32x32x16_f16(A[0][ks], bv0, acc[0][0], 0, 0, 0);
      acc[0][1] = __builtin_amdgcn_mfma_f32_32x32x16_f16(A[0][ks], bv1, acc[0][1], 0, 0, 0);
      acc[1][0] = __builtin_amdgcn_mfma_f32_32x32x16_f16(A[1][ks], bv0, acc[1][0], 0, 0, 0);
      acc[1][1] = __builtin_amdgcn_mfma_f32_32x32x16_f16(A[1][ks], bv1, acc[1][1], 0, 0, 0);
    }
  };

  int e = mask ? (int)__builtin_ctz((unsigned)mask) : -1;
  if (e >= 0) LDA(A0, e * 9);

  __syncthreads();   // xs + gates visible; barrier-free from here through phase 1

#pragma unroll 1
  while (e >= 0) {
    int nm  = (e < 7) ? (mask >> (e + 1)) : 0;
    int nxt = nm ? e + 1 + (int)__builtin_ctz((unsigned)nm) : -1;
    float g = ((const float*)(sm + GSM_OFF))[e];

#pragma unroll
    for (int mi = 0; mi < 2; ++mi) {
      f32x16 ebv;
#pragma unroll
      for (int rr = 0; rr < 16; ++rr)
        ebv[rr] = eb[e * 128 + m0 + mi * 32 + (rr & 3) + 8 * (rr >> 2) + 4 * l5];
      acc[mi][0] = ebv;
      acc[mi][1] = ebv;
    }

    const int t = e * 9;
    LDA(A1, t + 1); TAP(0, 0, A0);
    LDA(A0, t + 2); TAP(0, 1, A1);
    LDA(A1, t + 3); TAP(0, 2, A0);
    LDA(A0, t + 4); TAP(1, 0, A1);
    LDA(A1, t + 5); TAP(1, 1, A0);
    LDA(A0, t + 6); TAP(1, 2, A1);
    LDA(A1, t + 7); TAP(2, 0, A0);
    LDA(A0, t + 8); TAP(2, 1, A1);
    if (nxt >= 0) LDA(A1, nxt * 9);
    TAP(2, 2, A0);
#pragma unroll
    for (int mi = 0; mi < 2; ++mi)
#pragma unroll
      for (int ks = 0; ks < 4; ++ks) A0[mi][ks] = A1[mi][ks];

    __half2 g2 = __floats2half2_rn(g, g);
#pragma unroll
    for (int mi = 0; mi < 2; ++mi)
#pragma unroll
      for (int ni = 0; ni < 2; ++ni)
#pragma unroll
        for (int h = 0; h < 8; ++h) {
          float v0 = fmaxf(acc[mi][ni][2 * h],     0.f);
          float v1 = fmaxf(acc[mi][ni][2 * h + 1], 0.f);
          comb[mi][ni][h] = __hfma2(g2, __floats2half2_rn(v0, v1), comb[mi][ni][h]);
        }
    e = nxt;
  }

  // ---- store comb to LDS [pxl 128][co 128], chunk pos = (co>>3)^(pxl&15) ----
  char* cbase = sm + XS_BYTES;
#pragma unroll
  for (int mi = 0; mi < 2; ++mi)
#pragma unroll
    for (int ni = 0; ni < 2; ++ni) {
      int pxl = n0 + ni * 32 + l31;
      char* rowp = cbase + pxl * 256;
      int sw = pxl & 15;
#pragma unroll
      for (int q = 0; q < 4; ++q) {
        int co = m0 + mi * 32 + 8 * q + 4 * l5;
        int off = (((co >> 3) ^ sw) << 4) + (co & 7) * 2;
        uint2 u;
        u.x = *(unsigned*)&comb[mi][ni][2 * q];
        u.y = *(unsigned*)&comb[mi][ni][2 * q + 1];
        *(uint2*)(rowp + off) = u;
      }
    }

  __syncthreads();   // comb visible

  // ---- phase 2: 1x1 conv (M=128px, N=128co2, K=128co) + bias, interior write ----
  const int pm0 = (wv >> 1) * 64;   // pixel tile
  const int pn0 = (wv & 1) * 64;    // co2 tile
  f32x16 acc2[2][2];
#pragma unroll
  for (int mi = 0; mi < 2; ++mi)
#pragma unroll
    for (int ni = 0; ni < 2; ++ni)
#pragma unroll
      for (int rr = 0; rr < 16; ++rr) acc2[mi][ni][rr] = 0.f;

  const char* fwp = ws + FW_OFF;
#pragma unroll
  for (int ks = 0; ks < 8; ++ks) {
    f16x8 av[2], bvv[2];
#pragma unroll
    for (int mi = 0; mi < 2; ++mi) {
      int pxl = pm0 + mi * 32 + l31;
      av[mi] = *(const f16x8*)(cbase + pxl * 256 + ((((ks << 1) | l5) ^ (pxl & 15)) << 4));
    }
#pragma unroll
    for (int ni = 0; ni < 2; ++ni) {
      int co2 = pn0 + ni * 32 + l31;
      bvv[ni] = *(const f16x8*)(fwp + co2 * 256 + (((ks << 1) | l5) << 4));
    }
#pragma unroll
    for (int mi = 0; mi < 2; ++mi)
#pragma unroll
      for (int ni = 0; ni < 2; ++ni)
        acc2[mi][ni] = __builtin_amdgcn_mfma_f32_32x32x16_f16(av[mi], bvv[ni], acc2[mi][ni], 0, 0, 0);
  }

#pragma unroll
  for (int mi = 0; mi < 2; ++mi)
#pragma unroll
    for (int ni = 0; ni < 2; ++ni) {
      int co2 = pn0 + ni * 32 + l31;
      float bias = fb[co2];
      float* obase = out + (size_t)(b * 128 + co2) * 98 * 98;
#pragma unroll
      for (int q = 0; q < 4; ++q) {
        int pxl = pm0 + mi * 32 + 8 * q + 4 * l5;
        int y  = py * 16 + half * 8 + (pxl >> 4) + 1;
        int xg = px * 16 + (pxl & 15) + 1;
        float4 vv = make_float4(acc2[mi][ni][4 * q + 0] + bias, acc2[mi][ni][4 * q + 1] + bias,
                                acc2[mi][ni][4 * q + 2] + bias, acc2[mi][ni][4 * q + 3] + bias);
        __builtin_memcpy(obase + y * 98 + xg, &vv, 16);
      }
    }
}

extern "C" void kernel_launch(void* const* d_in, const int* in_sizes, int n_in,
                              void* d_out, int out_size, void* d_ws, size_t ws_size,
                              hipStream_t stream) {
  const float* x   = (const float*)d_in[0];
  const float* ew  = (const float*)d_in[1];
  const float* ebp = (const float*)d_in[2];
  const float* rw  = (const float*)d_in[3];
  const float* rb  = (const float*)d_in[4];
  const float* fw  = (const float*)d_in[5];
  const float* fb  = (const float*)d_in[6];
  const float* thr = (const float*)d_in[7];
  float* out = (float*)d_out;
  char* ws = (char*)d_ws;

  hipLaunchKernelGGL(pce_prep, dim3(296), dim3(256), 0, stream, ew, fw, ws);
  hipLaunchKernelGGL(pce_main, dim3(576), dim3(256), 0, stream,
                     x, ebp, rw, rb, thr, ws, fb, out);
}